// Round 2
// baseline (45.590 us; speedup 1.0000x reference)
//
#include <hip/hip_runtime.h>
#include <math.h>

#define HWSZ 262144          // 512*512
#define NCOPY 16             // partial-G copies to spread atomics
#define LAMBD 0.005f
#define SMOOTH 1e-6f

typedef __attribute__((ext_vector_type(8))) short bf16x8;
typedef __attribute__((ext_vector_type(4))) float f32x4;

static __device__ __forceinline__ unsigned short f2bf(float f) {
    unsigned int u = __float_as_uint(f);
    u += 0x7FFFu + ((u >> 16) & 1u);   // round-to-nearest-even
    return (unsigned short)(u >> 16);
}

// One 64-pixel tile per block (4096 blocks): maximal TLP, one barrier/block.
// LDS 16.9KB + VGPR 52 -> 8 blocks/CU resident (32 waves = full occupancy);
// inter-block overlap hides global-load latency instead of intra-block
// pipelining. 264-short row stride keeps ds_write_b128/ds_read_b128 at the
// structural 8-cycle floor (bank = 4*((r+g)%8), 8 lanes per 4-bank group).
__global__ __launch_bounds__(256) void gram_kernel(
    const float* __restrict__ X,   // input  [16][4][512][512]
    const float* __restrict__ T,   // target [16][4][512][512]
    float* __restrict__ Gpart)     // [NCOPY][32][32]
{
    __shared__ unsigned short w[32][264];

    const int tid  = threadIdx.x;
    const int b    = tid >> 4;             // batch 0..15 (producer role)
    const int px4  = (tid & 15) << 2;      // pixel offset within tile, x4
    const int lane = tid & 63;
    const int wv   = tid >> 6;
    const int r    = lane & 15;
    const int g    = lane >> 4;
    const int I    = (wv >> 1) << 4;       // G row tile base
    const int J    = (wv & 1) << 4;        // G col tile base

    const int pixBase = blockIdx.x << 6;   // 64 pixels per block

    // ---- global loads: 4 pixels x 4 channels x {input,target} ----
    float fi[16], ft[16];
    #pragma unroll
    for (int c = 0; c < 4; ++c) {
        size_t off = (size_t)(b * 4 + c) * HWSZ + pixBase + px4;
        *(float4*)&fi[c * 4] = *(const float4*)(X + off);
        *(float4*)&ft[c * 4] = *(const float4*)(T + off);
    }

    // ---- per-pixel softplus/confidence/softmax (f32), pack bf16 ----
    unsigned short pv[16] __attribute__((aligned(16)));
    unsigned short qv[16] __attribute__((aligned(16)));
    #pragma unroll
    for (int p = 0; p < 4; ++p) {
        float t0 = ft[p], t1 = ft[4 + p], t2 = ft[8 + p], t3 = ft[12 + p];
        // stable softplus: max(t,0) + log(1 + exp(-|t|))
        float sp0 = fmaxf(t0, 0.f) + __logf(1.f + __expf(-fabsf(t0)));
        float sp1 = fmaxf(t1, 0.f) + __logf(1.f + __expf(-fabsf(t1)));
        float sp2 = fmaxf(t2, 0.f) + __logf(1.f + __expf(-fabsf(t2)));
        float sp3 = fmaxf(t3, 0.f) + __logf(1.f + __expf(-fabsf(t3)));
        float S    = sp0 + sp1 + sp2 + sp3 + 4.0f;   // mm_S
        float conf = __expf(-4.0f / S);

        // p = softmax(input): +1 shift cancels; |x| small enough that the
        // max-subtraction is unnecessary in f32 (exp(7) ~ 1e3 << overflow)
        float e0 = __expf(fi[p]),     e1 = __expf(fi[4 + p]);
        float e2 = __expf(fi[8 + p]), e3 = __expf(fi[12 + p]);
        float inv = 1.f / (e0 + e1 + e2 + e3);
        pv[p * 4 + 0] = f2bf(e0 * inv);
        pv[p * 4 + 1] = f2bf(e1 * inv);
        pv[p * 4 + 2] = f2bf(e2 * inv);
        pv[p * 4 + 3] = f2bf(e3 * inv);

        // q = softmax((target+1)*conf)
        float q0 = __expf((t0 + 1.f) * conf), q1 = __expf((t1 + 1.f) * conf);
        float q2 = __expf((t2 + 1.f) * conf), q3 = __expf((t3 + 1.f) * conf);
        float qi = 1.f / (q0 + q1 + q2 + q3);
        qv[p * 4 + 0] = f2bf(q0 * qi);
        qv[p * 4 + 1] = f2bf(q1 * qi);
        qv[p * 4 + 2] = f2bf(q2 * qi);
        qv[p * 4 + 3] = f2bf(q3 * qi);
    }

    // column k = px*4 + c  (contiguous 16 shorts per thread per row)
    *(bf16x8*)&w[b][px4 * 4]          = *(const bf16x8*)&pv[0];
    *(bf16x8*)&w[b][px4 * 4 + 8]      = *(const bf16x8*)&pv[8];
    *(bf16x8*)&w[16 + b][px4 * 4]     = *(const bf16x8*)&qv[0];
    *(bf16x8*)&w[16 + b][px4 * 4 + 8] = *(const bf16x8*)&qv[8];
    __syncthreads();

    // ---- MFMA: this wave's 16x16 tile of G over K=256 ----
    f32x4 acc = {0.f, 0.f, 0.f, 0.f};
    #pragma unroll
    for (int kc = 0; kc < 8; ++kc) {
        bf16x8 a  = *(const bf16x8*)&w[I + r][kc * 32 + g * 8];
        bf16x8 bb = *(const bf16x8*)&w[J + r][kc * 32 + g * 8];
        acc = __builtin_amdgcn_mfma_f32_16x16x32_bf16(a, bb, acc, 0, 0, 0);
    }

    // C/D layout: col = lane&15, row = (lane>>4)*4 + reg
    float* dst = Gpart + (size_t)(blockIdx.x & (NCOPY - 1)) * 1024;
    #pragma unroll
    for (int v = 0; v < 4; ++v) {
        int row = I + g * 4 + v;
        int col = J + r;
        atomicAdd(&dst[row * 32 + col], acc[v]);
    }
}

__global__ __launch_bounds__(256) void loss_kernel(
    const float* __restrict__ Gpart, float* __restrict__ out)
{
    __shared__ float G[1024];
    __shared__ float red[4];
    const int t = threadIdx.x;

    for (int e = t; e < 1024; e += 256) {
        float s = 0.f;
        #pragma unroll
        for (int c = 0; c < NCOPY; ++c) s += Gpart[c * 1024 + e];
        G[e] = s;
    }
    __syncthreads();

    float local = 0.f;
    for (int e = t; e < 1024; e += 256) {
        int i = e >> 5, j = e & 31;
        float num = 2.f * G[(i << 5) | (j ^ 16)] + SMOOTH;
        float den = G[i * 33] + G[(j ^ 16) * 33] + SMOOTH;
        float D = num / den;
        if (j == (i ^ 16)) D = 0.f;                      // mask (i, i±B)
        local += (i == j) ? (D - 1.f) * (D - 1.f) : LAMBD * D * D;
    }

    #pragma unroll
    for (int off = 32; off; off >>= 1) local += __shfl_down(local, off);
    if ((t & 63) == 0) red[t >> 6] = local;
    __syncthreads();
    if (t == 0) out[0] = red[0] + red[1] + red[2] + red[3];
}

extern "C" void kernel_launch(void* const* d_in, const int* in_sizes, int n_in,
                              void* d_out, int out_size, void* d_ws, size_t ws_size,
                              hipStream_t stream)
{
    const float* X = (const float*)d_in[0];   // input
    const float* T = (const float*)d_in[1];   // target
    float* Gpart = (float*)d_ws;              // NCOPY * 1024 floats

    hipMemsetAsync(Gpart, 0, NCOPY * 1024 * sizeof(float), stream);
    gram_kernel<<<4096, 256, 0, stream>>>(X, T, Gpart);
    loss_kernel<<<1, 256, 0, stream>>>(Gpart, (float*)d_out);
}

// Round 3
// 40.600 us; speedup vs baseline: 1.1229x; 1.1229x over previous
//
#include <hip/hip_runtime.h>
#include <math.h>

#define HWSZ 262144          // 512*512
#define NCOPY 16             // partial-G copies to spread atomics
#define LAMBD 0.005f
#define SMOOTH 1e-6f

typedef __attribute__((ext_vector_type(8))) short bf16x8;
typedef __attribute__((ext_vector_type(4))) float f32x4;
typedef __attribute__((ext_vector_type(4))) int i32x4;

// v_rcp_f32: <=1 ulp approx reciprocal; avoids the ~9-instr IEEE div sequence
static __device__ __forceinline__ float rcp_hw(float x) {
    float r; asm("v_rcp_f32 %0, %1" : "=v"(r) : "v"(x)); return r;
}
// v_cvt_pk_bf16_f32: 2 f32 -> packed 2x bf16 (RTE), 1 instr (no builtin, m240)
static __device__ __forceinline__ unsigned int pk_bf16(float lo, float hi) {
    unsigned int r;
    asm("v_cvt_pk_bf16_f32 %0, %1, %2" : "=v"(r) : "v"(lo), "v"(hi));
    return r;
}

// One 64-pixel tile per block (4096 blocks). VALU-lean inner math:
//  - sum softplus = log(prod(1+e^t))  (1 log instead of 4, no fmax/fabs)
//  - v_rcp_f32 for all reciprocals (softmax norms + conf argument)
//  - v_cvt_pk_bf16_f32 for bf16 packing (1 instr / 2 values, RTE)
// LDS 264-short row stride keeps ds_write_b128/ds_read_b128 conflict-free.
__global__ __launch_bounds__(256) void gram_kernel(
    const float* __restrict__ X,   // input  [16][4][512][512]
    const float* __restrict__ T,   // target [16][4][512][512]
    float* __restrict__ Gpart)     // [NCOPY][32][32]
{
    __shared__ unsigned short w[32][264];

    const int tid  = threadIdx.x;
    const int b    = tid >> 4;             // batch 0..15 (producer role)
    const int px4  = (tid & 15) << 2;      // pixel offset within tile, x4
    const int lane = tid & 63;
    const int wv   = tid >> 6;
    const int r    = lane & 15;
    const int g    = lane >> 4;
    const int I    = (wv >> 1) << 4;       // G row tile base
    const int J    = (wv & 1) << 4;        // G col tile base

    const int pixBase = blockIdx.x << 6;   // 64 pixels per block

    // ---- global loads: 4 pixels x 4 channels x {input,target} ----
    float fi[16], ft[16];
    #pragma unroll
    for (int c = 0; c < 4; ++c) {
        size_t off = (size_t)(b * 4 + c) * HWSZ + pixBase + px4;
        *(float4*)&fi[c * 4] = *(const float4*)(X + off);
        *(float4*)&ft[c * 4] = *(const float4*)(T + off);
    }

    // ---- per-pixel softplus/confidence/softmax (f32), pack bf16 ----
    unsigned int pu[8], qu[8];
    #pragma unroll
    for (int p = 0; p < 4; ++p) {
        float t0 = ft[p], t1 = ft[4 + p], t2 = ft[8 + p], t3 = ft[12 + p];

        // S = sum_c softplus(t_c) + 4 = log(prod_c (1+e^{t_c})) + 4
        // (sum t_c^+ < ~25 -> prod < 1e11, safely inside f32 range)
        float prod = (1.f + __expf(t0)) * (1.f + __expf(t1))
                   * (1.f + __expf(t2)) * (1.f + __expf(t3));
        float S    = __logf(prod) + 4.0f;
        float conf = __expf(-4.0f * rcp_hw(S));

        // p = softmax(input) (+1 shift cancels; |x|<~6 so no max needed)
        float e0 = __expf(fi[p]),     e1 = __expf(fi[4 + p]);
        float e2 = __expf(fi[8 + p]), e3 = __expf(fi[12 + p]);
        float inv = rcp_hw(e0 + e1 + e2 + e3);
        pu[p * 2]     = pk_bf16(e0 * inv, e1 * inv);
        pu[p * 2 + 1] = pk_bf16(e2 * inv, e3 * inv);

        // q = softmax((t+1)*conf), (t+1)*conf = fma(t, conf, conf)
        float q0 = __expf(fmaf(t0, conf, conf));
        float q1 = __expf(fmaf(t1, conf, conf));
        float q2 = __expf(fmaf(t2, conf, conf));
        float q3 = __expf(fmaf(t3, conf, conf));
        float qi = rcp_hw(q0 + q1 + q2 + q3);
        qu[p * 2]     = pk_bf16(q0 * qi, q1 * qi);
        qu[p * 2 + 1] = pk_bf16(q2 * qi, q3 * qi);
    }

    // column k = px*4 + c (16 consecutive shorts per thread per row)
    *(i32x4*)&w[b][px4 * 4]          = *(const i32x4*)&pu[0];
    *(i32x4*)&w[b][px4 * 4 + 8]      = *(const i32x4*)&pu[4];
    *(i32x4*)&w[16 + b][px4 * 4]     = *(const i32x4*)&qu[0];
    *(i32x4*)&w[16 + b][px4 * 4 + 8] = *(const i32x4*)&qu[4];
    __syncthreads();

    // ---- MFMA: this wave's 16x16 tile of G over K=256 ----
    f32x4 acc = {0.f, 0.f, 0.f, 0.f};
    #pragma unroll
    for (int kc = 0; kc < 8; ++kc) {
        bf16x8 a  = *(const bf16x8*)&w[I + r][kc * 32 + g * 8];
        bf16x8 bb = *(const bf16x8*)&w[J + r][kc * 32 + g * 8];
        acc = __builtin_amdgcn_mfma_f32_16x16x32_bf16(a, bb, acc, 0, 0, 0);
    }

    // C/D layout: col = lane&15, row = (lane>>4)*4 + reg
    float* dst = Gpart + (size_t)(blockIdx.x & (NCOPY - 1)) * 1024;
    #pragma unroll
    for (int v = 0; v < 4; ++v) {
        int row = I + g * 4 + v;
        int col = J + r;
        atomicAdd(&dst[row * 32 + col], acc[v]);
    }
}

__global__ __launch_bounds__(256) void loss_kernel(
    const float* __restrict__ Gpart, float* __restrict__ out)
{
    __shared__ float G[1024];
    __shared__ float red[4];
    const int t = threadIdx.x;

    for (int e = t; e < 1024; e += 256) {
        float s = 0.f;
        #pragma unroll
        for (int c = 0; c < NCOPY; ++c) s += Gpart[c * 1024 + e];
        G[e] = s;
    }
    __syncthreads();

    float local = 0.f;
    for (int e = t; e < 1024; e += 256) {
        int i = e >> 5, j = e & 31;
        float num = 2.f * G[(i << 5) | (j ^ 16)] + SMOOTH;
        float den = G[i * 33] + G[(j ^ 16) * 33] + SMOOTH;
        float D = num / den;
        if (j == (i ^ 16)) D = 0.f;                      // mask (i, i±B)
        local += (i == j) ? (D - 1.f) * (D - 1.f) : LAMBD * D * D;
    }

    #pragma unroll
    for (int off = 32; off; off >>= 1) local += __shfl_down(local, off);
    if ((t & 63) == 0) red[t >> 6] = local;
    __syncthreads();
    if (t == 0) out[0] = red[0] + red[1] + red[2] + red[3];
}

extern "C" void kernel_launch(void* const* d_in, const int* in_sizes, int n_in,
                              void* d_out, int out_size, void* d_ws, size_t ws_size,
                              hipStream_t stream)
{
    const float* X = (const float*)d_in[0];   // input
    const float* T = (const float*)d_in[1];   // target
    float* Gpart = (float*)d_ws;              // NCOPY * 1024 floats

    hipMemsetAsync(Gpart, 0, NCOPY * 1024 * sizeof(float), stream);
    gram_kernel<<<4096, 256, 0, stream>>>(X, T, Gpart);
    loss_kernel<<<1, 256, 0, stream>>>(Gpart, (float*)d_out);
}

// Round 4
// 36.166 us; speedup vs baseline: 1.2606x; 1.1226x over previous
//
#include <hip/hip_runtime.h>
#include <math.h>

#define HWSZ 262144          // 512*512
#define NCOPY 16             // partial-G copies to spread atomics
#define LAMBD 0.005f
#define SMOOTH 1e-6f

typedef __attribute__((ext_vector_type(8))) short bf16x8;
typedef __attribute__((ext_vector_type(4))) float f32x4;
typedef __attribute__((ext_vector_type(4))) int i32x4;

// v_rcp_f32: <=1 ulp approx reciprocal; avoids the ~9-instr IEEE div sequence
static __device__ __forceinline__ float rcp_hw(float x) {
    float r; asm("v_rcp_f32 %0, %1" : "=v"(r) : "v"(x)); return r;
}
// v_cvt_pk_bf16_f32: 2 f32 -> packed 2x bf16 (RTE), 1 instr (no builtin, m240)
static __device__ __forceinline__ unsigned int pk_bf16(float lo, float hi) {
    unsigned int r;
    asm("v_cvt_pk_bf16_f32 %0, %1, %2" : "=v"(r) : "v"(lo), "v"(hi));
    return r;
}

// 1024 blocks x 4 tiles: register-accumulated Gram tile, ONE atomic flush per
// block (1.05M atomics vs 4.19M: WRITE_SIZE showed atomics write through to
// the memory-side coherence point, 1:1 with count -> cut them 4x).
// Double-buffered LDS, one barrier per tile; next tile's global loads are
// issued before the current tile's math so HBM latency hides under
// math+MFMA. 4 blocks/CU resident (LDS 33.8KB), 16 waves/CU.
__global__ __launch_bounds__(256) void gram_kernel(
    const float* __restrict__ X,   // input  [16][4][512][512]
    const float* __restrict__ T,   // target [16][4][512][512]
    float* __restrict__ Gpart)     // [NCOPY][32][32]
{
    __shared__ unsigned short w[2][32][264];

    const int tid  = threadIdx.x;
    const int b    = tid >> 4;             // batch 0..15 (producer role)
    const int px4  = (tid & 15) << 2;      // pixel offset within tile, x4
    const int lane = tid & 63;
    const int wv   = tid >> 6;
    const int r    = lane & 15;
    const int g    = lane >> 4;
    const int I    = (wv >> 1) << 4;       // G row tile base
    const int J    = (wv & 1) << 4;        // G col tile base

    const int tile0 = blockIdx.x << 2;     // 4 tiles of 64 pixels per block

    float fr[2][16], tr[2][16];            // ping-pong staging (static idx after unroll)

    // prologue: issue tile-0 loads
    #pragma unroll
    for (int c = 0; c < 4; ++c) {
        size_t off = (size_t)(b * 4 + c) * HWSZ + (tile0 << 6) + px4;
        *(float4*)&fr[0][c * 4] = *(const float4*)(X + off);
        *(float4*)&tr[0][c * 4] = *(const float4*)(T + off);
    }

    f32x4 acc = {0.f, 0.f, 0.f, 0.f};

    #pragma unroll 4
    for (int t = 0; t < 4; ++t) {
        const int cur = t & 1, nxt = cur ^ 1;   // static after unroll

        // ---- prefetch next tile (overlaps with this tile's math/MFMA) ----
        if (t < 3) {
            #pragma unroll
            for (int c = 0; c < 4; ++c) {
                size_t off = (size_t)(b * 4 + c) * HWSZ + ((tile0 + t + 1) << 6) + px4;
                *(float4*)&fr[nxt][c * 4] = *(const float4*)(X + off);
                *(float4*)&tr[nxt][c * 4] = *(const float4*)(T + off);
            }
        }

        // ---- per-pixel softplus/confidence/softmax (f32), pack bf16 ----
        unsigned int pu[8], qu[8];
        #pragma unroll
        for (int p = 0; p < 4; ++p) {
            float t0 = tr[cur][p],     t1 = tr[cur][4 + p];
            float t2 = tr[cur][8 + p], t3 = tr[cur][12 + p];

            // S = sum_c softplus(t_c) + 4 = log(prod_c (1+e^{t_c})) + 4
            float prod = (1.f + __expf(t0)) * (1.f + __expf(t1))
                       * (1.f + __expf(t2)) * (1.f + __expf(t3));
            float S    = __logf(prod) + 4.0f;
            float conf = __expf(-4.0f * rcp_hw(S));

            // p = softmax(input) (+1 shift cancels; range needs no max-sub)
            float e0 = __expf(fr[cur][p]),     e1 = __expf(fr[cur][4 + p]);
            float e2 = __expf(fr[cur][8 + p]), e3 = __expf(fr[cur][12 + p]);
            float inv = rcp_hw(e0 + e1 + e2 + e3);
            pu[p * 2]     = pk_bf16(e0 * inv, e1 * inv);
            pu[p * 2 + 1] = pk_bf16(e2 * inv, e3 * inv);

            // q = softmax((t+1)*conf)
            float q0 = __expf(fmaf(t0, conf, conf));
            float q1 = __expf(fmaf(t1, conf, conf));
            float q2 = __expf(fmaf(t2, conf, conf));
            float q3 = __expf(fmaf(t3, conf, conf));
            float qi = rcp_hw(q0 + q1 + q2 + q3);
            qu[p * 2]     = pk_bf16(q0 * qi, q1 * qi);
            qu[p * 2 + 1] = pk_bf16(q2 * qi, q3 * qi);
        }

        // column k = px*4 + c (16 consecutive shorts per thread per row)
        *(i32x4*)&w[cur][b][px4 * 4]          = *(const i32x4*)&pu[0];
        *(i32x4*)&w[cur][b][px4 * 4 + 8]      = *(const i32x4*)&pu[4];
        *(i32x4*)&w[cur][16 + b][px4 * 4]     = *(const i32x4*)&qu[0];
        *(i32x4*)&w[cur][16 + b][px4 * 4 + 8] = *(const i32x4*)&qu[4];
        __syncthreads();
        // (reads of w[cur] from tile t-2 are separated from this write by
        //  two barriers; one barrier per tile is sufficient with 2 buffers)

        // ---- MFMA: this wave's 16x16 tile of G, K=256, accumulate ----
        #pragma unroll
        for (int kc = 0; kc < 8; ++kc) {
            bf16x8 a  = *(const bf16x8*)&w[cur][I + r][kc * 32 + g * 8];
            bf16x8 bb = *(const bf16x8*)&w[cur][J + r][kc * 32 + g * 8];
            acc = __builtin_amdgcn_mfma_f32_16x16x32_bf16(a, bb, acc, 0, 0, 0);
        }
    }

    // C/D layout: col = lane&15, row = (lane>>4)*4 + reg
    float* dst = Gpart + (size_t)(blockIdx.x & (NCOPY - 1)) * 1024;
    #pragma unroll
    for (int v = 0; v < 4; ++v) {
        int row = I + g * 4 + v;
        int col = J + r;
        atomicAdd(&dst[row * 32 + col], acc[v]);
    }
}

__global__ __launch_bounds__(256) void loss_kernel(
    const float* __restrict__ Gpart, float* __restrict__ out)
{
    __shared__ float G[1024];
    __shared__ float red[4];
    const int t = threadIdx.x;

    {   // vectorized copy-reduction: thread t owns elements [4t, 4t+4)
        f32x4 s = {0.f, 0.f, 0.f, 0.f};
        #pragma unroll
        for (int c = 0; c < NCOPY; ++c)
            s += *(const f32x4*)&Gpart[c * 1024 + t * 4];
        *(f32x4*)&G[t * 4] = s;
    }
    __syncthreads();

    float local = 0.f;
    for (int e = t; e < 1024; e += 256) {
        int i = e >> 5, j = e & 31;
        float num = 2.f * G[(i << 5) | (j ^ 16)] + SMOOTH;
        float den = G[i * 33] + G[(j ^ 16) * 33] + SMOOTH;
        float D = num / den;
        if (j == (i ^ 16)) D = 0.f;                      // mask (i, i±B)
        local += (i == j) ? (D - 1.f) * (D - 1.f) : LAMBD * D * D;
    }

    #pragma unroll
    for (int off = 32; off; off >>= 1) local += __shfl_down(local, off);
    if ((t & 63) == 0) red[t >> 6] = local;
    __syncthreads();
    if (t == 0) out[0] = red[0] + red[1] + red[2] + red[3];
}

extern "C" void kernel_launch(void* const* d_in, const int* in_sizes, int n_in,
                              void* d_out, int out_size, void* d_ws, size_t ws_size,
                              hipStream_t stream)
{
    const float* X = (const float*)d_in[0];   // input
    const float* T = (const float*)d_in[1];   // target
    float* Gpart = (float*)d_ws;              // NCOPY * 1024 floats

    hipMemsetAsync(Gpart, 0, NCOPY * 1024 * sizeof(float), stream);
    gram_kernel<<<1024, 256, 0, stream>>>(X, T, Gpart);
    loss_kernel<<<1, 256, 0, stream>>>(Gpart, (float*)d_out);
}